// Round 7
// baseline (476.973 us; speedup 1.0000x reference)
//
#include <hip/hip_runtime.h>
#include <hip/hip_fp16.h>

#define D 64
#define TB 256

// Bucketing: users 1024 nodes/bucket, artists 256 nodes/bucket.
#define BSHIFT_U 10
#define BSHIFT_A 8
#define CAP 12288   // fixed per-bucket record capacity (mean 10240, sigma ~101)
#define NXCD 8

typedef _Float16 half8 __attribute__((ext_vector_type(8)));
typedef float float8 __attribute__((ext_vector_type(8)));

__device__ __forceinline__ float8 h8_to_f8(half8 h) {
    return __builtin_convertvector(h, float8);
}

__global__ __launch_bounds__(TB) void zero_ints_kernel(int* __restrict__ p, int n) {
    int i = blockIdx.x * blockDim.x + threadIdx.x;
    int stride = gridDim.x * blockDim.x;
    for (; i < n; i += stride) p[i] = 0;
}

// fp32 -> fp16 row conversion (8 elems per thread)
__global__ __launch_bounds__(TB) void cvt_f16_kernel(const float4* __restrict__ in,
                                                     half8* __restrict__ out, int n8) {
    int i = blockIdx.x * blockDim.x + threadIdx.x;
    int stride = gridDim.x * blockDim.x;
    for (; i < n8; i += stride) {
        float4 a = in[i * 2 + 0];
        float4 b = in[i * 2 + 1];
        half8 h;
        h[0] = (_Float16)a.x; h[1] = (_Float16)a.y; h[2] = (_Float16)a.z; h[3] = (_Float16)a.w;
        h[4] = (_Float16)b.x; h[5] = (_Float16)b.y; h[6] = (_Float16)b.z; h[7] = (_Float16)b.w;
        out[i] = h;
    }
}

// XCD-owned fixed-capacity partition. Group g = blockIdx&7 (round-robin -> one
// XCD per group). Each group's 64 blocks sweep the full edge list but write
// only owned buckets: user bucket b owned by (b&7)==g, artist bucket bb owned
// by ((bb+NBu)&7)==g (phase shift so local_csr_both's block b -> XCD mapping
// matches ownership). All writers of a bucket share one L2 -> no cross-XCD
// partial-line churn. Ownership is a perf heuristic only; correctness is
// mapping-independent.
__global__ __launch_bounds__(TB) void partition_both_kernel(const int* __restrict__ art,
                                                            const int* __restrict__ usr, int E,
                                                            int* __restrict__ bcur_u,
                                                            int* __restrict__ bcur_a,
                                                            unsigned* __restrict__ part_u,
                                                            unsigned* __restrict__ part_a,
                                                            int NBu, int NBa) {
    __shared__ int cu[256], bu[256], ca[256], ba[256];
    const int g   = blockIdx.x & (NXCD - 1);
    const int sub = blockIdx.x >> 3;
    const int nsub = gridDim.x >> 3;
    for (int i = threadIdx.x; i < NBu; i += TB) cu[i] = 0;
    for (int i = threadIdx.x; i < NBa; i += TB) ca[i] = 0;
    __syncthreads();
    int chunk = (E + nsub - 1) / nsub;
    int e0 = sub * chunk;
    int e1 = min(E, e0 + chunk);
    for (int e = e0 + threadIdx.x; e < e1; e += TB) {
        int bui = usr[e] >> BSHIFT_U;
        if ((bui & (NXCD - 1)) == g) atomicAdd(&cu[bui], 1);
        int bai = art[e] >> BSHIFT_A;
        if (((bai + NBu) & (NXCD - 1)) == g) atomicAdd(&ca[bai], 1);
    }
    __syncthreads();
    for (int i = threadIdx.x; i < NBu; i += TB) {
        int c = cu[i];
        bu[i] = c ? (i * CAP + atomicAdd(&bcur_u[i], c)) : 0;
        cu[i] = 0;
    }
    for (int i = threadIdx.x; i < NBa; i += TB) {
        int c = ca[i];
        ba[i] = c ? (i * CAP + atomicAdd(&bcur_a[i], c)) : 0;
        ca[i] = 0;
    }
    __syncthreads();
    for (int e = e0 + threadIdx.x; e < e1; e += TB) {
        int a = art[e];
        int u = usr[e];
        int bui = u >> BSHIFT_U;
        if ((bui & (NXCD - 1)) == g) {
            int lu = atomicAdd(&cu[bui], 1);
            part_u[bu[bui] + lu] = ((unsigned)a << BSHIFT_U) | ((unsigned)u & ((1u << BSHIFT_U) - 1u));
        }
        int bai = a >> BSHIFT_A;
        if (((bai + NBu) & (NXCD - 1)) == g) {
            int la = atomicAdd(&ca[bai], 1);
            part_a[ba[bai] + la] = ((unsigned)u << BSHIFT_A) | ((unsigned)a & ((1u << BSHIFT_A) - 1u));
        }
    }
}

// Shared body: LDS hist over <=1024 local nodes, LDS scan, per-node {beg,deg}
// int2 write, then local CSR fill confined to the bucket's contiguous span.
__device__ __forceinline__ void local_csr_body(const unsigned* __restrict__ part,
                                               int ecount, int ebeg, int n0,
                                               int2* __restrict__ rowdeg,
                                               int* __restrict__ csr,
                                               int N, int NPB, int BSHIFT,
                                               int* cnt, int* sdata) {
    const int tid = threadIdx.x;
    const int eend = ebeg + ecount;
    const unsigned mask = (unsigned)(NPB - 1);
    for (int i = tid; i < NPB; i += TB) cnt[i] = 0;
    __syncthreads();
    for (int e = ebeg + tid; e < eend; e += TB)
        atomicAdd(&cnt[part[e] & mask], 1);
    __syncthreads();
    const int ITEMS = NPB >> 8;  // 4 (users) or 1 (artists)
    const int ib = tid * ITEMS;
    int local = 0;
    for (int k = 0; k < ITEMS; ++k) local += cnt[ib + k];
    sdata[tid] = local;
    __syncthreads();
    for (int off = 1; off < TB; off <<= 1) {
        int t = (tid >= off) ? sdata[tid - off] : 0;
        __syncthreads();
        if (tid >= off) sdata[tid] += t;
        __syncthreads();
    }
    int run = sdata[tid] - local;
    for (int k = 0; k < ITEMS; ++k) {
        int v = cnt[ib + k];
        cnt[ib + k] = run;  // becomes the fill cursor
        int n = n0 + ib + k;
        if (n < N) rowdeg[n] = make_int2(ebeg + run, v);
        run += v;
    }
    __syncthreads();
    for (int e = ebeg + tid; e < eend; e += TB) {
        unsigned r = part[e];
        int l = (int)(r & mask);
        int pos = atomicAdd(&cnt[l], 1);
        csr[ebeg + pos] = (int)(r >> BSHIFT);
    }
}

// Both directions in one dispatch: blocks [0,NBu) user buckets, [NBu,NBu+NBa)
// artist buckets. Block b lands on XCD b%8 == bucket owner -> part reads are L2-hits.
__global__ __launch_bounds__(TB) void local_csr_both_kernel(const unsigned* __restrict__ part_u,
                                                            const unsigned* __restrict__ part_a,
                                                            const int* __restrict__ bcur_u,
                                                            const int* __restrict__ bcur_a,
                                                            int2* __restrict__ rowdeg_u,
                                                            int2* __restrict__ rowdeg_a,
                                                            int* __restrict__ csr_u,
                                                            int* __restrict__ csr_a,
                                                            int NU, int NA, int NBu) {
    __shared__ int cnt[1024];
    __shared__ int sdata[TB];
    const int b = blockIdx.x;
    if (b < NBu) {
        local_csr_body(part_u, bcur_u[b], b * CAP, b << BSHIFT_U,
                       rowdeg_u, csr_u, NU, 1 << BSHIFT_U, BSHIFT_U, cnt, sdata);
    } else {
        const int bb = b - NBu;
        local_csr_body(part_a, bcur_a[bb], bb * CAP, bb << BSHIFT_A,
                       rowdeg_a, csr_a, NA, 1 << BSHIFT_A, BSHIFT_A, cnt, sdata);
    }
}

// 8-lane group per destination node (lane = half8 chunk); 8 nodes per wave.
// fp16 sources, fp32 accumulate.
//  x_out != nullptr   : write fp16 layer output
//  fin_out != nullptr : fused final epilogue (Mode A last layer):
//                       fin_out = scale*(fin_in0 + fin_x1 + fin_x2 + x)
//  final_acc != nullptr: Mode B fused RMW (+ init from fp32 input at layer 0)
__global__ __launch_bounds__(TB) void gather_mean_kernel(const half8* __restrict__ src,
                                                         const int* __restrict__ csr,
                                                         const int2* __restrict__ rowdeg,
                                                         half8* __restrict__ x_out,
                                                         float4* __restrict__ final_acc,
                                                         const float4* __restrict__ init_src,
                                                         const float4* __restrict__ fin_in0,
                                                         const half8* __restrict__ fin_x1,
                                                         const half8* __restrict__ fin_x2,
                                                         float4* __restrict__ fin_out,
                                                         int N, float scale) {
    const int lane = threadIdx.x & 7;
    int g = (blockIdx.x * blockDim.x + threadIdx.x) >> 3;
    const int ngroups = (gridDim.x * blockDim.x) >> 3;
    for (int n = g; n < N; n += ngroups) {
        const int2 rd = rowdeg[n];
        const int beg = rd.x;
        const int dg = rd.y;
        const int end = beg + dg;
        float8 a0 = 0.f, a1 = 0.f, a2 = 0.f, a3 = 0.f;
        int e = beg;
        for (; e + 4 <= end; e += 4) {
            const int s0 = csr[e + 0];
            const int s1 = csr[e + 1];
            const int s2 = csr[e + 2];
            const int s3 = csr[e + 3];
            const half8 v0 = src[s0 * 8 + lane];
            const half8 v1 = src[s1 * 8 + lane];
            const half8 v2 = src[s2 * 8 + lane];
            const half8 v3 = src[s3 * 8 + lane];
            a0 += h8_to_f8(v0);
            a1 += h8_to_f8(v1);
            a2 += h8_to_f8(v2);
            a3 += h8_to_f8(v3);
        }
        for (; e < end; ++e)
            a0 += h8_to_f8(src[csr[e] * 8 + lane]);
        float8 s = (a0 + a1) + (a2 + a3);
        const float inv = 1.f / (float)(dg > 0 ? dg : 1);
        float8 x = s * inv;
        const int o8 = n * 8 + lane;
        if (x_out != nullptr) {
            half8 h;
            for (int k = 0; k < 8; ++k) h[k] = (_Float16)x[k];
            x_out[o8] = h;
        }
        const int fo = n * (D / 4) + lane * 2;  // float4 index into fp32 arrays
        if (fin_out != nullptr) {
            float8 t = h8_to_f8(fin_x1[o8]) + h8_to_f8(fin_x2[o8]) + x;
            float4 f0 = fin_in0[fo + 0];
            float4 f1 = fin_in0[fo + 1];
            f0.x = (f0.x + t[0]) * scale; f0.y = (f0.y + t[1]) * scale;
            f0.z = (f0.z + t[2]) * scale; f0.w = (f0.w + t[3]) * scale;
            f1.x = (f1.x + t[4]) * scale; f1.y = (f1.y + t[5]) * scale;
            f1.z = (f1.z + t[6]) * scale; f1.w = (f1.w + t[7]) * scale;
            fin_out[fo + 0] = f0;
            fin_out[fo + 1] = f1;
        }
        if (final_acc != nullptr) {
            float4 f0, f1;
            if (init_src != nullptr) {
                f0 = init_src[fo + 0];
                f1 = init_src[fo + 1];
                f0.x *= scale; f0.y *= scale; f0.z *= scale; f0.w *= scale;
                f1.x *= scale; f1.y *= scale; f1.z *= scale; f1.w *= scale;
            } else {
                f0 = final_acc[fo + 0];
                f1 = final_acc[fo + 1];
            }
            f0.x += x[0] * scale; f0.y += x[1] * scale; f0.z += x[2] * scale; f0.w += x[3] * scale;
            f1.x += x[4] * scale; f1.y += x[5] * scale; f1.z += x[6] * scale; f1.w += x[7] * scale;
            final_acc[fo + 0] = f0;
            final_acc[fo + 1] = f1;
        }
    }
}

extern "C" void kernel_launch(void* const* d_in, const int* in_sizes, int n_in,
                              void* d_out, int out_size, void* d_ws, size_t ws_size,
                              hipStream_t stream) {
    const float* x_users   = (const float*)d_in[0];
    const float* x_artists = (const float*)d_in[1];
    const int*   a2u       = (const int*)d_in[2];  // row0: artist(src), row1: user(dst)

    const int NU = in_sizes[0] / D;
    const int NA = in_sizes[1] / D;
    const int E  = in_sizes[2] / 2;
    const int* art = a2u;        // edge source (artist id)
    const int* usr = a2u + E;    // edge target (user id)

    const float scale = 0.25f;   // 1/(NUM_LAYERS+1)

    const int NBu = (NU + (1 << BSHIFT_U) - 1) >> BSHIFT_U;  // 196
    const int NBa = (NA + (1 << BSHIFT_A) - 1) >> BSHIFT_A;  // 196

    // ---- workspace layout (256B aligned) ----
    char* w = (char*)d_ws;
    size_t off = 0;
    auto alloc = [&](size_t bytes) -> char* {
        char* p = w + off;
        off += (bytes + 255) & ~(size_t)255;
        return p;
    };
    int2* rowdeg_u = (int2*)alloc((size_t)NU * 8);
    int2* rowdeg_a = (int2*)alloc((size_t)NA * 8);
    int* bcur      = (int*)alloc((size_t)(NBu + NBa) * 4);
    int* bcur_u    = bcur;
    int* bcur_a    = bcur + NBu;
    int* csr_u     = (int*)alloc((size_t)NBu * CAP * 4);  // artist ids grouped by user
    int* csr_a     = (int*)alloc((size_t)NBa * CAP * 4);  // user ids grouped by artist
    half8* xa_in   = (half8*)alloc((size_t)NA * D * 2);   // fp16 copy of x_artists
    // part arrays; dead after local_csr -> reused as the x_a layer buffers
    unsigned* part_u = (unsigned*)alloc((size_t)NBu * CAP * 4);
    unsigned* part_a = (unsigned*)alloc((size_t)NBa * CAP * 4);

    const size_t XU = (size_t)NU * D * 2;                 // 25.6 MB
    const size_t XA = (size_t)NA * D * 2;                 // 6.4 MB
    const size_t XUa = (XU + 255) & ~(size_t)255;
    const size_t XAa = (XA + 255) & ~(size_t)255;

    // Mode A: 3 separate x_u buffers + fused final in last-layer gathers;
    // Mode B: single x_u buffer, final RMW fused into every gather.
    const bool modeA = (off + 3 * XUa) <= ws_size;

    half8* x_u1 = (half8*)alloc(XU);
    half8* x_u2 = modeA ? (half8*)alloc(XU) : x_u1;
    half8* x_u3 = modeA ? (half8*)alloc(XU) : x_u1;
    // x_a buffers overlay the (dead-after-build) part region: 3*6.4MB <= 19.27MB
    char* part_base = (char*)part_u;
    half8* x_a1 = (half8*)(part_base);
    half8* x_a2 = modeA ? (half8*)(part_base + XAa) : x_a1;
    half8* x_a3 = modeA ? (half8*)(part_base + 2 * XAa) : x_a1;

    float* out_u = (float*)d_out;
    float* out_a = out_u + (size_t)NU * D;

    // ---- fp16 source conversion + XCD-owned fixed-cap bucketed CSR build ----
    cvt_f16_kernel<<<1024, TB, 0, stream>>>((const float4*)x_artists, xa_in, NA * D / 8);
    zero_ints_kernel<<<1, TB, 0, stream>>>(bcur, NBu + NBa);
    partition_both_kernel<<<512, TB, 0, stream>>>(art, usr, E, bcur_u, bcur_a,
                                                  part_u, part_a, NBu, NBa);
    local_csr_both_kernel<<<NBu + NBa, TB, 0, stream>>>(part_u, part_a, bcur_u, bcur_a,
                                                        rowdeg_u, rowdeg_a,
                                                        csr_u, csr_a, NU, NA, NBu);

    // ---- 3 propagation layers ----
    half8* xu_buf[3] = {x_u1, x_u2, x_u3};
    half8* xa_buf[3] = {x_a1, x_a2, x_a3};
    const half8* srcA = xa_in;
    for (int l = 0; l < 3; ++l) {
        const bool last = (l == 2);
        // users <- artists
        gather_mean_kernel<<<4096, TB, 0, stream>>>(
            srcA, csr_u, rowdeg_u, xu_buf[l],
            modeA ? nullptr : (float4*)out_u,
            (!modeA && l == 0) ? (const float4*)x_users : nullptr,
            (modeA && last) ? (const float4*)x_users : nullptr,
            (modeA && last) ? x_u1 : nullptr,
            (modeA && last) ? x_u2 : nullptr,
            (modeA && last) ? (float4*)out_u : nullptr,
            NU, scale);
        // artists <- users
        gather_mean_kernel<<<4096, TB, 0, stream>>>(
            xu_buf[l], csr_a, rowdeg_a,
            (modeA && last) ? nullptr : xa_buf[l],   // x_a3 dead in Mode A
            modeA ? nullptr : (float4*)out_a,
            (!modeA && l == 0) ? (const float4*)x_artists : nullptr,
            (modeA && last) ? (const float4*)x_artists : nullptr,
            (modeA && last) ? x_a1 : nullptr,
            (modeA && last) ? x_a2 : nullptr,
            (modeA && last) ? (float4*)out_a : nullptr,
            NA, scale);
        srcA = xa_buf[l];
    }
}

// Round 8
// 376.539 us; speedup vs baseline: 1.2667x; 1.2667x over previous
//
#include <hip/hip_runtime.h>
#include <hip/hip_fp16.h>

#define D 64
#define TB 256

// Bucketing: users 1024 nodes/bucket, artists 256 nodes/bucket.
#define BSHIFT_U 10
#define BSHIFT_A 8
#define CAP   12288   // csr per-bucket capacity (actual edges; mean 10204, ~20 sigma)
#define CAP_P 16384   // part per-bucket capacity (padded;      mean 12252, ~33 sigma)
#define SENT  0xFFFFFFFFu

typedef _Float16 half8 __attribute__((ext_vector_type(8)));
typedef float float8 __attribute__((ext_vector_type(8)));

__device__ __forceinline__ float8 h8_to_f8(half8 h) {
    return __builtin_convertvector(h, float8);
}

__global__ __launch_bounds__(TB) void zero_ints_kernel(int* __restrict__ p, int n) {
    int i = blockIdx.x * blockDim.x + threadIdx.x;
    int stride = gridDim.x * blockDim.x;
    for (; i < n; i += stride) p[i] = 0;
}

// fp32 -> fp16 row conversion (8 elems per thread)
__global__ __launch_bounds__(TB) void cvt_f16_kernel(const float4* __restrict__ in,
                                                     half8* __restrict__ out, int n8) {
    int i = blockIdx.x * blockDim.x + threadIdx.x;
    int stride = gridDim.x * blockDim.x;
    for (; i < n8; i += stride) {
        float4 a = in[i * 2 + 0];
        float4 b = in[i * 2 + 1];
        half8 h;
        h[0] = (_Float16)a.x; h[1] = (_Float16)a.y; h[2] = (_Float16)a.z; h[3] = (_Float16)a.w;
        h[4] = (_Float16)b.x; h[5] = (_Float16)b.y; h[6] = (_Float16)b.z; h[7] = (_Float16)b.w;
        out[i] = h;
    }
}

// Line-owned padded partition: each block claims per-bucket runs rounded up to
// whole 64B lines (16 records), so every part cache line is written entirely
// by one block -> no cross-XCD partial-line churn. Pad slots get SENT.
// record_u = (art << BSHIFT_U) | (usr & 1023); record_a = (usr << BSHIFT_A) | (art & 255)
__global__ __launch_bounds__(TB) void partition_both_kernel(const int* __restrict__ art,
                                                            const int* __restrict__ usr, int E,
                                                            int* __restrict__ bcur_u,
                                                            int* __restrict__ bcur_a,
                                                            unsigned* __restrict__ part_u,
                                                            unsigned* __restrict__ part_a,
                                                            int NBu, int NBa) {
    __shared__ int cu[256], bu[256], ca[256], ba[256];
    for (int i = threadIdx.x; i < NBu; i += TB) cu[i] = 0;
    for (int i = threadIdx.x; i < NBa; i += TB) ca[i] = 0;
    __syncthreads();
    int chunk = (E + gridDim.x - 1) / gridDim.x;
    int e0 = blockIdx.x * chunk;
    int e1 = min(E, e0 + chunk);
    for (int e = e0 + threadIdx.x; e < e1; e += TB) {
        atomicAdd(&cu[usr[e] >> BSHIFT_U], 1);
        atomicAdd(&ca[art[e] >> BSHIFT_A], 1);
    }
    __syncthreads();
    for (int i = threadIdx.x; i < NBu; i += TB) {
        int c = cu[i];
        bu[i] = c ? (i * CAP_P + atomicAdd(&bcur_u[i], (c + 15) & ~15)) : 0;
        cu[i] = 0;
    }
    for (int i = threadIdx.x; i < NBa; i += TB) {
        int c = ca[i];
        ba[i] = c ? (i * CAP_P + atomicAdd(&bcur_a[i], (c + 15) & ~15)) : 0;
        ca[i] = 0;
    }
    __syncthreads();
    for (int e = e0 + threadIdx.x; e < e1; e += TB) {
        int a = art[e];
        int u = usr[e];
        int bui = u >> BSHIFT_U;
        int lu = atomicAdd(&cu[bui], 1);
        part_u[bu[bui] + lu] = ((unsigned)a << BSHIFT_U) | ((unsigned)u & ((1u << BSHIFT_U) - 1u));
        int bai = a >> BSHIFT_A;
        int la = atomicAdd(&ca[bai], 1);
        part_a[ba[bai] + la] = ((unsigned)u << BSHIFT_A) | ((unsigned)a & ((1u << BSHIFT_A) - 1u));
    }
    __syncthreads();
    // sentinel-fill each claimed run's pad tail (completes the owned lines)
    for (int i = threadIdx.x; i < NBu; i += TB) {
        int c = cu[i];
        if (c) {
            int pad = (c + 15) & ~15;
            for (int k = c; k < pad; ++k) part_u[bu[i] + k] = SENT;
        }
    }
    for (int i = threadIdx.x; i < NBa; i += TB) {
        int c = ca[i];
        if (c) {
            int pad = (c + 15) & ~15;
            for (int k = c; k < pad; ++k) part_a[ba[i] + k] = SENT;
        }
    }
}

// Shared body: sentinel-aware LDS hist over <=1024 local nodes, LDS scan,
// per-node {beg,deg} int2 write, then local CSR fill confined to the bucket's
// contiguous span.
__device__ __forceinline__ void local_csr_body(const unsigned* __restrict__ part,
                                               int ecount, int ebeg_p, int ebeg_c, int n0,
                                               int2* __restrict__ rowdeg,
                                               int* __restrict__ csr,
                                               int N, int NPB, int BSHIFT,
                                               int* cnt, int* sdata) {
    const int tid = threadIdx.x;
    const int eend = ebeg_p + ecount;
    const unsigned mask = (unsigned)(NPB - 1);
    for (int i = tid; i < NPB; i += TB) cnt[i] = 0;
    __syncthreads();
    for (int e = ebeg_p + tid; e < eend; e += TB) {
        unsigned r = part[e];
        if (r != SENT) atomicAdd(&cnt[r & mask], 1);
    }
    __syncthreads();
    const int ITEMS = NPB >> 8;  // 4 (users) or 1 (artists)
    const int ib = tid * ITEMS;
    int local = 0;
    for (int k = 0; k < ITEMS; ++k) local += cnt[ib + k];
    sdata[tid] = local;
    __syncthreads();
    for (int off = 1; off < TB; off <<= 1) {
        int t = (tid >= off) ? sdata[tid - off] : 0;
        __syncthreads();
        if (tid >= off) sdata[tid] += t;
        __syncthreads();
    }
    int run = sdata[tid] - local;
    for (int k = 0; k < ITEMS; ++k) {
        int v = cnt[ib + k];
        cnt[ib + k] = run;  // becomes the fill cursor
        int n = n0 + ib + k;
        if (n < N) rowdeg[n] = make_int2(ebeg_c + run, v);
        run += v;
    }
    __syncthreads();
    for (int e = ebeg_p + tid; e < eend; e += TB) {
        unsigned r = part[e];
        if (r == SENT) continue;
        int l = (int)(r & mask);
        int pos = atomicAdd(&cnt[l], 1);
        csr[ebeg_c + pos] = (int)(r >> BSHIFT);
    }
}

// Both directions in one dispatch: blocks [0,NBu) user buckets, [NBu,NBu+NBa) artists.
__global__ __launch_bounds__(TB) void local_csr_both_kernel(const unsigned* __restrict__ part_u,
                                                            const unsigned* __restrict__ part_a,
                                                            const int* __restrict__ bcur_u,
                                                            const int* __restrict__ bcur_a,
                                                            int2* __restrict__ rowdeg_u,
                                                            int2* __restrict__ rowdeg_a,
                                                            int* __restrict__ csr_u,
                                                            int* __restrict__ csr_a,
                                                            int NU, int NA, int NBu) {
    __shared__ int cnt[1024];
    __shared__ int sdata[TB];
    const int b = blockIdx.x;
    if (b < NBu) {
        local_csr_body(part_u, bcur_u[b], b * CAP_P, b * CAP, b << BSHIFT_U,
                       rowdeg_u, csr_u, NU, 1 << BSHIFT_U, BSHIFT_U, cnt, sdata);
    } else {
        const int bb = b - NBu;
        local_csr_body(part_a, bcur_a[bb], bb * CAP_P, bb * CAP, bb << BSHIFT_A,
                       rowdeg_a, csr_a, NA, 1 << BSHIFT_A, BSHIFT_A, cnt, sdata);
    }
}

// 8-lane group per destination node (lane = half8 chunk); 8 nodes per wave.
// fp16 sources, fp32 accumulate.
//  x_out != nullptr   : write fp16 layer output
//  fin_out != nullptr : fused final epilogue (Mode A last layer):
//                       fin_out = scale*(fin_in0 + fin_x1 + fin_x2 + x)
//  final_acc != nullptr: Mode B fused RMW (+ init from fp32 input at layer 0)
__global__ __launch_bounds__(TB) void gather_mean_kernel(const half8* __restrict__ src,
                                                         const int* __restrict__ csr,
                                                         const int2* __restrict__ rowdeg,
                                                         half8* __restrict__ x_out,
                                                         float4* __restrict__ final_acc,
                                                         const float4* __restrict__ init_src,
                                                         const float4* __restrict__ fin_in0,
                                                         const half8* __restrict__ fin_x1,
                                                         const half8* __restrict__ fin_x2,
                                                         float4* __restrict__ fin_out,
                                                         int N, float scale) {
    const int lane = threadIdx.x & 7;
    int g = (blockIdx.x * blockDim.x + threadIdx.x) >> 3;
    const int ngroups = (gridDim.x * blockDim.x) >> 3;
    for (int n = g; n < N; n += ngroups) {
        const int2 rd = rowdeg[n];
        const int beg = rd.x;
        const int dg = rd.y;
        const int end = beg + dg;
        float8 a0 = 0.f, a1 = 0.f, a2 = 0.f, a3 = 0.f;
        int e = beg;
        for (; e + 4 <= end; e += 4) {
            const int s0 = csr[e + 0];
            const int s1 = csr[e + 1];
            const int s2 = csr[e + 2];
            const int s3 = csr[e + 3];
            const half8 v0 = src[s0 * 8 + lane];
            const half8 v1 = src[s1 * 8 + lane];
            const half8 v2 = src[s2 * 8 + lane];
            const half8 v3 = src[s3 * 8 + lane];
            a0 += h8_to_f8(v0);
            a1 += h8_to_f8(v1);
            a2 += h8_to_f8(v2);
            a3 += h8_to_f8(v3);
        }
        for (; e < end; ++e)
            a0 += h8_to_f8(src[csr[e] * 8 + lane]);
        float8 s = (a0 + a1) + (a2 + a3);
        const float inv = 1.f / (float)(dg > 0 ? dg : 1);
        float8 x = s * inv;
        const int o8 = n * 8 + lane;
        if (x_out != nullptr) {
            half8 h;
            for (int k = 0; k < 8; ++k) h[k] = (_Float16)x[k];
            x_out[o8] = h;
        }
        const int fo = n * (D / 4) + lane * 2;  // float4 index into fp32 arrays
        if (fin_out != nullptr) {
            float8 t = h8_to_f8(fin_x1[o8]) + h8_to_f8(fin_x2[o8]) + x;
            float4 f0 = fin_in0[fo + 0];
            float4 f1 = fin_in0[fo + 1];
            f0.x = (f0.x + t[0]) * scale; f0.y = (f0.y + t[1]) * scale;
            f0.z = (f0.z + t[2]) * scale; f0.w = (f0.w + t[3]) * scale;
            f1.x = (f1.x + t[4]) * scale; f1.y = (f1.y + t[5]) * scale;
            f1.z = (f1.z + t[6]) * scale; f1.w = (f1.w + t[7]) * scale;
            fin_out[fo + 0] = f0;
            fin_out[fo + 1] = f1;
        }
        if (final_acc != nullptr) {
            float4 f0, f1;
            if (init_src != nullptr) {
                f0 = init_src[fo + 0];
                f1 = init_src[fo + 1];
                f0.x *= scale; f0.y *= scale; f0.z *= scale; f0.w *= scale;
                f1.x *= scale; f1.y *= scale; f1.z *= scale; f1.w *= scale;
            } else {
                f0 = final_acc[fo + 0];
                f1 = final_acc[fo + 1];
            }
            f0.x += x[0] * scale; f0.y += x[1] * scale; f0.z += x[2] * scale; f0.w += x[3] * scale;
            f1.x += x[4] * scale; f1.y += x[5] * scale; f1.z += x[6] * scale; f1.w += x[7] * scale;
            final_acc[fo + 0] = f0;
            final_acc[fo + 1] = f1;
        }
    }
}

extern "C" void kernel_launch(void* const* d_in, const int* in_sizes, int n_in,
                              void* d_out, int out_size, void* d_ws, size_t ws_size,
                              hipStream_t stream) {
    const float* x_users   = (const float*)d_in[0];
    const float* x_artists = (const float*)d_in[1];
    const int*   a2u       = (const int*)d_in[2];  // row0: artist(src), row1: user(dst)

    const int NU = in_sizes[0] / D;
    const int NA = in_sizes[1] / D;
    const int E  = in_sizes[2] / 2;
    const int* art = a2u;        // edge source (artist id)
    const int* usr = a2u + E;    // edge target (user id)

    const float scale = 0.25f;   // 1/(NUM_LAYERS+1)

    const int NBu = (NU + (1 << BSHIFT_U) - 1) >> BSHIFT_U;  // 196
    const int NBa = (NA + (1 << BSHIFT_A) - 1) >> BSHIFT_A;  // 196

    // ---- workspace layout (256B aligned) ----
    char* w = (char*)d_ws;
    size_t off = 0;
    auto alloc = [&](size_t bytes) -> char* {
        char* p = w + off;
        off += (bytes + 255) & ~(size_t)255;
        return p;
    };
    int2* rowdeg_u = (int2*)alloc((size_t)NU * 8);
    int2* rowdeg_a = (int2*)alloc((size_t)NA * 8);
    int* bcur      = (int*)alloc((size_t)(NBu + NBa) * 4);
    int* bcur_u    = bcur;
    int* bcur_a    = bcur + NBu;
    int* csr_u     = (int*)alloc((size_t)NBu * CAP * 4);  // artist ids grouped by user
    int* csr_a     = (int*)alloc((size_t)NBa * CAP * 4);  // user ids grouped by artist
    half8* xa_in   = (half8*)alloc((size_t)NA * D * 2);   // fp16 copy of x_artists
    // part arrays; dead after local_csr -> reused as the x_a layer buffers
    unsigned* part_u = (unsigned*)alloc((size_t)NBu * CAP_P * 4);
    unsigned* part_a = (unsigned*)alloc((size_t)NBa * CAP_P * 4);

    const size_t XU = (size_t)NU * D * 2;                 // 25.6 MB
    const size_t XA = (size_t)NA * D * 2;                 // 6.4 MB
    const size_t XUa = (XU + 255) & ~(size_t)255;
    const size_t XAa = (XA + 255) & ~(size_t)255;

    // Mode A: 3 separate x_u buffers + fused final in last-layer gathers;
    // Mode B: single x_u buffer, final RMW fused into every gather.
    const bool modeA = (off + 3 * XUa) <= ws_size;

    half8* x_u1 = (half8*)alloc(XU);
    half8* x_u2 = modeA ? (half8*)alloc(XU) : x_u1;
    half8* x_u3 = modeA ? (half8*)alloc(XU) : x_u1;
    // x_a buffers overlay the (dead-after-build) part region: 3*6.4MB <= 25.7MB
    char* part_base = (char*)part_u;
    half8* x_a1 = (half8*)(part_base);
    half8* x_a2 = modeA ? (half8*)(part_base + XAa) : x_a1;
    half8* x_a3 = modeA ? (half8*)(part_base + 2 * XAa) : x_a1;

    float* out_u = (float*)d_out;
    float* out_a = out_u + (size_t)NU * D;

    // ---- fp16 source conversion + line-owned fixed-cap bucketed CSR build ----
    cvt_f16_kernel<<<1024, TB, 0, stream>>>((const float4*)x_artists, xa_in, NA * D / 8);
    zero_ints_kernel<<<1, TB, 0, stream>>>(bcur, NBu + NBa);
    partition_both_kernel<<<256, TB, 0, stream>>>(art, usr, E, bcur_u, bcur_a,
                                                  part_u, part_a, NBu, NBa);
    local_csr_both_kernel<<<NBu + NBa, TB, 0, stream>>>(part_u, part_a, bcur_u, bcur_a,
                                                        rowdeg_u, rowdeg_a,
                                                        csr_u, csr_a, NU, NA, NBu);

    // ---- 3 propagation layers ----
    half8* xu_buf[3] = {x_u1, x_u2, x_u3};
    half8* xa_buf[3] = {x_a1, x_a2, x_a3};
    const half8* srcA = xa_in;
    for (int l = 0; l < 3; ++l) {
        const bool last = (l == 2);
        // users <- artists
        gather_mean_kernel<<<4096, TB, 0, stream>>>(
            srcA, csr_u, rowdeg_u, xu_buf[l],
            modeA ? nullptr : (float4*)out_u,
            (!modeA && l == 0) ? (const float4*)x_users : nullptr,
            (modeA && last) ? (const float4*)x_users : nullptr,
            (modeA && last) ? x_u1 : nullptr,
            (modeA && last) ? x_u2 : nullptr,
            (modeA && last) ? (float4*)out_u : nullptr,
            NU, scale);
        // artists <- users
        gather_mean_kernel<<<4096, TB, 0, stream>>>(
            xu_buf[l], csr_a, rowdeg_a,
            (modeA && last) ? nullptr : xa_buf[l],   // x_a3 dead in Mode A
            modeA ? nullptr : (float4*)out_a,
            (!modeA && l == 0) ? (const float4*)x_artists : nullptr,
            (modeA && last) ? (const float4*)x_artists : nullptr,
            (modeA && last) ? x_a1 : nullptr,
            (modeA && last) ? x_a2 : nullptr,
            (modeA && last) ? (float4*)out_a : nullptr,
            NA, scale);
        srcA = xa_buf[l];
    }
}